// Round 6
// baseline (133.129 us; speedup 1.0000x reference)
//
#include <hip/hip_runtime.h>
#include <stdint.h>

// out[n,o] = sum_{d,i} q[n,d] x[n,i] W1[d,i,o] + (q @ b1)[n,o]
// GEMM M=4096 N=256 K=16384 (k = d*256 + i), fp16 MFMA 32x32x16, fp32 accum.
//
// ROUND 6: occupancy + de-convoy. Rounds 3-5 all pinned at MfmaUtil~26% =
// exactly (MFMA demand)/(duration) with 2 waves/SIMD: waves stall in lockstep
// load bursts (same-CU blocks shared icoff -> convoy), and 2 waves/SIMD can't
// fill the gaps. Fix: tile 32x32, grid 1024 = 128 mb x 8 nc, ring depth 8,
// __launch_bounds__(256,4) -> 4 blocks/CU (16 waves/CU), and icoff stagger
// that splits the 4 same-CU blocks into 2 aligned pairs (L1 reuse) offset by
// 8 ics (convoy broken). MFMA floor/SIMD unchanged: 4 waves x 256 x 32 cy =
// 13.65 us. prep-W vectorized (float4 over o, 16 B/lane).

typedef _Float16 f16;
typedef f16 f16x8 __attribute__((ext_vector_type(8)));
typedef float f32x16 __attribute__((ext_vector_type(16)));

#define QDIM 64

// one fp32-float8 -> f16x8
#define XFRAG(DST, PTR)                                      \
  do {                                                       \
    float4 a_ = *(const float4*)(PTR);                       \
    float4 b_ = *(const float4*)((PTR) + 4);                 \
    f16x8 h_;                                                \
    h_[0] = (f16)a_.x; h_[1] = (f16)a_.y; h_[2] = (f16)a_.z; \
    h_[3] = (f16)a_.w; h_[4] = (f16)b_.x; h_[5] = (f16)b_.y; \
    h_[6] = (f16)b_.z; h_[7] = (f16)b_.w;                    \
    DST = h_;                                                \
  } while (0)

// ---------------- prep ----------------
// Wt layout (8 MB):  byte = ((nc*64 + d)*16 + ic)*1024 + hf*512 + c*16 + j*2
//   <- W1[d][ic*16 + hf*8 + j][nc*32 + c]      (B-frag lane-linear, 1KB chunks)
// Xt layout (2 MB):  byte = ((mb64*16 + ic)*2 + hf)*1024 + row*16 + j*2
//   <- x[mb64*64 + row][ic*16 + hf*8 + j]      (A-frag lane-linear, 64-row tiles)
// Bt layout (32 KB): byte = ((nc*4 + kc)*2 + hf)*512 + c*16 + j*2
//   <- b1[kc*16 + hf*8 + j][nc*32 + c]
// grid 577: [0,512) W | [512,576) Xt | 576 Bt
__global__ __launch_bounds__(256) void prep(const float* __restrict__ W,
                                            const float* __restrict__ B1,
                                            const float* __restrict__ X,
                                            f16* __restrict__ Wt,
                                            f16* __restrict__ Xt,
                                            f16* __restrict__ Bt) {
  const int b = blockIdx.x, t = threadIdx.x;
  if (b < 512) {
    // vectorized: each lane loads float4 over o (16 B), 8 j's, emits 4 f16x8
    const int d = b >> 3, grp = b & 7;
    const int ibL = t >> 6;           // 0..3
    const int ib = (grp << 2) + ibL;  // i = ib*8 + j
    const int o0 = (t & 63) << 2;     // 4 consecutive o per lane
    const int ic = ib >> 1, hb = ib & 1;
    float v[32];
#pragma unroll
    for (int j = 0; j < 8; ++j) {
      float4 f = *(const float4*)(W + ((size_t)d * 256 + (ib << 3) + j) * 256 + o0);
      v[j * 4 + 0] = f.x; v[j * 4 + 1] = f.y;
      v[j * 4 + 2] = f.z; v[j * 4 + 3] = f.w;
    }
#pragma unroll
    for (int oo = 0; oo < 4; ++oo) {
      const int o = o0 + oo, ncb = o >> 5, c = o & 31;
      f16x8 h;
#pragma unroll
      for (int j = 0; j < 8; ++j) h[j] = (f16)v[j * 4 + oo];
      *(f16x8*)((char*)Wt + ((((size_t)ncb * 64 + d) * 16 + ic) << 10) +
                (hb << 9) + (c << 4)) = h;
    }
  } else if (b < 576) {
    const int mb = b - 512;  // 64-row tiles
#pragma unroll
    for (int rep = 0; rep < 8; ++rep) {
      const int u = (rep << 8) + t;          // 0..2047
      const int row = u & 63, ish = u >> 6;  // ish 0..31, i = ish*8 + j
      const float* src = X + ((size_t)((mb << 6) + row)) * 256 + (ish << 3);
      f16x8 h;
      XFRAG(h, src);
      *(f16x8*)((char*)Xt + ((((size_t)mb * 16 + (ish >> 1)) * 2 + (ish & 1)) << 10) +
                (row << 4)) = h;
    }
  } else {
#pragma unroll
    for (int kb = 0; kb < 8; ++kb) {  // k = kb*8 + j
      const float* src = B1 + ((size_t)kb << 3) * 256 + t;
      f16x8 h;
#pragma unroll
      for (int j = 0; j < 8; ++j) h[j] = (f16)src[(size_t)j << 8];
      *(f16x8*)((char*)Bt + (((size_t)(t >> 5) * 4 + (kb >> 1)) << 10) +
                ((kb & 1) << 9) + ((t & 31) << 4)) = h;
    }
  }
}

// ---- main: 1024 blocks = 128 mb-tiles (32 rows) x 8 col-tiles (32 cols) ----
// 4 waves split d into ranges of 16 (full K per block); LDS cross-wave reduce.
__global__ __launch_bounds__(256, 4) void mlp_main(const float* __restrict__ Q,
                                                   const f16* __restrict__ Wt,
                                                   const f16* __restrict__ Xt,
                                                   const f16* __restrict__ Bt,
                                                   float* __restrict__ out) {
  __shared__ __align__(16) float red[4][32][36];

  const int bid = blockIdx.x;
  const int nc = bid & 7;   // XCD-affine column tile
  const int mb = bid >> 3;  // 0..127, 32-row tile
  const int t = threadIdx.x;
  const int w = t >> 6;     // wave owns d-range [w*16, w*16+16)
  const int l = t & 63;
  const int l31 = l & 31;
  const int hf = l >> 5;

  // per-lane W base: chunk (dq, ic) at + (dq*16 + ic)*1024
  const char* wl = (const char*)Wt + (((size_t)(nc * 64 + (w << 4))) << 14) +
                   (hf << 9) + (l31 << 4);
  // per-lane x base: frag (ic) at + ic*2048 (row = (mb&1)*32 + l31 in 64-row tile)
  const char* xb = (const char*)Xt + ((size_t)(mb >> 1) << 15) + (hf << 10) +
                   ((size_t)(((mb & 1) << 5) + l31) << 4);

  // q scalars: q[mb*32 + l31][w*16 + i]
  f16 qr[16];
  {
    const float* qp = Q + ((size_t)((mb << 5) + l31)) * QDIM + (w << 4);
#pragma unroll
    for (int g = 0; g < 4; ++g) {
      float4 v = *(const float4*)(qp + (g << 2));
      qr[g * 4 + 0] = (f16)v.x; qr[g * 4 + 1] = (f16)v.y;
      qr[g * 4 + 2] = (f16)v.z; qr[g * 4 + 3] = (f16)v.w;
    }
  }

  f32x16 acc[2];
#pragma unroll
  for (int p = 0; p < 2; ++p)
#pragma unroll
    for (int r = 0; r < 16; ++r) acc[p][r] = 0.f;

  f16x8 Wr[8], xfA, xfB;

  // phase stagger: same-CU quad = {p, p+8, p, p+8} -> 2 aligned pairs (L1
  // reuse), pairs de-phased by half a walk (no convoy).
  const int icoff = (((mb & 7) << 1) | (((mb >> 5) & 1) << 3)) & 15;

  xfA = *(const f16x8*)(xb + ((size_t)icoff << 11));
#pragma unroll
  for (int i = 0; i < 8; ++i)
    Wr[i] = *(const f16x8*)(wl + (((size_t)(i * 16 + icoff)) << 10));

  for (int s = 0; s < 16; ++s) {
    const int ic = (icoff + s) & 15;
    const int icn = (icoff + s + 1) & 15;
    xfB = *(const f16x8*)(xb + ((size_t)icn << 11));
    // half 0: consume (ic, dq 0..7), prefetch (ic, dq 8..15)
#pragma unroll
    for (int i = 0; i < 8; ++i) {
      f16x8 wfr = Wr[i];
      Wr[i] = *(const f16x8*)(wl + (((size_t)((8 + i) * 16 + ic)) << 10));
      f16x8 a = xfA * qr[i];
      acc[i & 1] = __builtin_amdgcn_mfma_f32_32x32x16_f16(a, wfr, acc[i & 1], 0, 0, 0);
    }
    // half 1: consume (ic, dq 8..15), prefetch (icn, dq 0..7)
    // (s==15: prefetch wraps to icoff -> 8 dead reloads, harmless)
#pragma unroll
    for (int i = 0; i < 8; ++i) {
      f16x8 wfr = Wr[i];
      Wr[i] = *(const f16x8*)(wl + (((size_t)(i * 16 + icn)) << 10));
      f16x8 a = xfA * qr[8 + i];
      acc[i & 1] = __builtin_amdgcn_mfma_f32_32x32x16_f16(a, wfr, acc[i & 1], 0, 0, 0);
    }
    xfA = xfB;
  }

  // merge chains
#pragma unroll
  for (int r = 0; r < 16; ++r) acc[0][r] += acc[1][r];

  // bias (wave 0 only): 4 chunks over QDIM, A = q-frag, B = Bt
  if (w == 0) {
#pragma unroll
    for (int kc = 0; kc < 4; ++kc) {
      f16x8 bf = *(const f16x8*)((const char*)Bt +
          (((size_t)nc * 4 + kc) << 10) + (hf << 9) + (l31 << 4));
      f16x8 q0;
      XFRAG(q0, Q + ((size_t)((mb << 5) + l31)) * QDIM + (kc << 4) + (hf << 3));
      acc[0] = __builtin_amdgcn_mfma_f32_32x32x16_f16(q0, bf, acc[0], 0, 0, 0);
    }
  }

  // cross-wave K-reduction in LDS.
  // C/D (32x32): col = lane&31, row = (reg&3) + 8*(reg>>2) + 4*(lane>>5)
#pragma unroll
  for (int r = 0; r < 16; ++r) {
    const int row0 = (r & 3) + ((r >> 2) << 3) + (hf << 2);
    red[w][row0][l31] = acc[0][r];
  }
  __syncthreads();

  const int row = t >> 3;        // 0..31
  const int cg = (t & 7) << 2;   // 0,4,...,28
  float4 sum = {0.f, 0.f, 0.f, 0.f};
#pragma unroll
  for (int wq = 0; wq < 4; ++wq) {
    float4 v = *(const float4*)(&red[wq][row][cg]);
    sum.x += v.x; sum.y += v.y; sum.z += v.z; sum.w += v.w;
  }
  *(float4*)(out + ((size_t)((mb << 5) + row)) * 256 + (nc << 5) + cg) = sum;
}

extern "C" void kernel_launch(void* const* d_in, const int* in_sizes, int n_in,
                              void* d_out, int out_size, void* d_ws, size_t ws_size,
                              hipStream_t stream) {
  (void)in_sizes; (void)n_in; (void)out_size; (void)ws_size;
  const float* x  = (const float*)d_in[0];   // [4096,256]
  const float* q  = (const float*)d_in[1];   // [4096,64]
  const float* W1 = (const float*)d_in[2];   // [64,256,256]
  const float* b1 = (const float*)d_in[3];   // [64,256]
  float* out = (float*)d_out;                // [4096,256] fp32

  // ws: Wt 8 MB | Bt 32 KB | Xt 2 MB  (~10.03 MB)
  f16* Wt = (f16*)d_ws;
  f16* Bt = (f16*)((char*)d_ws + ((size_t)8 << 20));
  f16* Xt = (f16*)((char*)d_ws + ((size_t)8 << 20) + 32768);

  prep<<<577, 256, 0, stream>>>(W1, b1, x, Wt, Xt, Bt);
  mlp_main<<<1024, 256, 0, stream>>>(q, Wt, Xt, Bt, out);
}